// Round 8
// baseline (257.013 us; speedup 1.0000x reference)
//
#include <hip/hip_runtime.h>
#include <math.h>

// Sizes from the reference
#define B_SZ 4096
#define GRID 2048            // persistent-ish: each block handles b and b+GRID
#define N_SZ 16
#define A_SZ 8
#define IN_DIM 128
#define OUT_DIM 128
#define D_OBS 128
#define ROW_OUT (D_OBS + A_SZ)   // 136 floats = 34 float4

// Native clang vector (required by __builtin_nontemporal_*)
typedef float f32x4 __attribute__((ext_vector_type(4)));

// ---------------------------------------------------------------------------
// Kernel 1: fold W_attn into W_fc.
//   v_src[i] = sum_o W_fc[o,i]*W_attn[o]; v_dst[i] = sum_o W_fc[o,i]*W_attn[128+o]
// ---------------------------------------------------------------------------
__global__ __launch_bounds__(1024) void prep_v(const float* __restrict__ W_fc,
                                               const float* __restrict__ W_attn,
                                               float* __restrict__ v) {
  __shared__ float part[8][2][128];
  const int i = threadIdx.x & 127;
  const int seg = threadIdx.x >> 7;
  float s = 0.f, d = 0.f;
  #pragma unroll
  for (int oo = 0; oo < 16; ++oo) {
    const int o = seg * 16 + oo;
    const float w = W_fc[o * IN_DIM + i];
    s += w * W_attn[o];
    d += w * W_attn[OUT_DIM + o];
  }
  part[seg][0][i] = s;
  part[seg][1][i] = d;
  __syncthreads();
  if (seg == 0) {
    float ss = 0.f, dd = 0.f;
    #pragma unroll
    for (int t = 0; t < 8; ++t) { ss += part[t][0][i]; dd += part[t][1][i]; }
    v[i] = ss;
    v[IN_DIM + i] = dd;
  }
}

// ---------------------------------------------------------------------------
// Per-b input registers (prefetched one iteration ahead).
// ---------------------------------------------------------------------------
struct Regs {
  f32x4 o0, o1;   // obs: thread holds obs[k0][d4] and obs[k0+8][d4], k0=tid>>5
  f32x4 h0, h1;   // h elements tid*8 .. tid*8+8
  float pp, pa;   // pol/act element tid (valid for tid<128)
};

__device__ __forceinline__ Regs load_b(const float* __restrict__ h,
                                       const float* __restrict__ pol,
                                       const float* __restrict__ act,
                                       const float* __restrict__ obs,
                                       int b, int tid) {
  Regs r;
  const f32x4* hp = (const f32x4*)(h + (size_t)b * (N_SZ * IN_DIM));
  r.h0 = __builtin_nontemporal_load(&hp[tid * 2]);
  r.h1 = __builtin_nontemporal_load(&hp[tid * 2 + 1]);
  const f32x4* op = (const f32x4*)(obs + (size_t)b * (N_SZ * D_OBS));
  r.o0 = __builtin_nontemporal_load(&op[tid]);
  r.o1 = __builtin_nontemporal_load(&op[tid + 256]);
  if (tid < 128) {
    r.pp = __builtin_nontemporal_load(&pol[(size_t)b * 128 + tid]);
    r.pa = __builtin_nontemporal_load(&act[(size_t)b * 128 + tid]);
  } else {
    r.pp = 0.f; r.pa = 0.f;
  }
  return r;
}

// ---------------------------------------------------------------------------
// Kernel 2: fused compute + replication. Grid = 2048 blocks x 256 threads;
// block handles b = bid and b + 2048 with a depth-2 load pipeline.
// Phase 4 is pure register->global NT stores (no LDS on the hot path).
// ---------------------------------------------------------------------------
__global__ __launch_bounds__(256) void gat_fused(
    const float* __restrict__ h,        // [B,16,128]
    const float* __restrict__ pol,      // [B,16,8]
    const float* __restrict__ act,      // [B,16,8]
    const float* __restrict__ obs,      // [B*16,128]
    const float* __restrict__ v,        // [256] (v_src | v_dst)
    float* __restrict__ out_obs,        // [B*16,16,136]
    float* __restrict__ out_w)          // [B*16,16,1]
{
  const int tid = threadIdx.x;

  __shared__ float a_src_sm[16];
  __shared__ float a_dst_sm[16];
  __shared__ float w_sm[256];        // [i][j]
  __shared__ float pol_sm[128];      // [j][a]
  __shared__ float act_sm[128];
  __shared__ float sumz_sm[128];     // [i][a]

  // v fragments for this thread's lane-in-row (constant across both b's)
  const int l = tid & 15;
  const f32x4* vs = (const f32x4*)v;
  const f32x4* vd = (const f32x4*)(v + IN_DIM);
  const f32x4 s0 = vs[l * 2], s1 = vs[l * 2 + 1];
  const f32x4 d0 = vd[l * 2], d1 = vd[l * 2 + 1];

  Regs cur = load_b(h, pol, act, obs, blockIdx.x, tid);
  Regs nxt = cur;

  #pragma unroll
  for (int it = 0; it < 2; ++it) {
    const int b = blockIdx.x + it * GRID;

    // --- stage small LDS ---
    if (tid < 128) { pol_sm[tid] = cur.pp; act_sm[tid] = cur.pa; }

    // --- phase 1: a_src/a_dst (16 lanes per row) ---
    {
      float s = cur.h0.x * s0.x + cur.h0.y * s0.y + cur.h0.z * s0.z + cur.h0.w * s0.w
              + cur.h1.x * s1.x + cur.h1.y * s1.y + cur.h1.z * s1.z + cur.h1.w * s1.w;
      float d = cur.h0.x * d0.x + cur.h0.y * d0.y + cur.h0.z * d0.z + cur.h0.w * d0.w
              + cur.h1.x * d1.x + cur.h1.y * d1.y + cur.h1.z * d1.z + cur.h1.w * d1.w;
      for (int m = 8; m >= 1; m >>= 1) {
        s += __shfl_xor(s, m, 16);
        d += __shfl_xor(d, m, 16);
      }
      if (l == 0) {
        a_src_sm[tid >> 4] = s;
        a_dst_sm[tid >> 4] = d;
      }
    }
    __syncthreads();

    // --- phase 2: w[i][j] ---
    float wv;
    {
      float e = a_src_sm[tid & 15] + a_dst_sm[tid >> 4];
      e = (e >= 0.f) ? e : 0.01f * e;
      wv = 1.f / (1.f + expf(-e));
      w_sm[tid] = wv;
      __builtin_nontemporal_store(wv, &out_w[(size_t)b * 256 + tid]);
    }
    __syncthreads();

    // --- phase 3a: sum_z[i][a] ---
    if (tid < 128) {
      const int i = tid >> 3, a = tid & 7;
      float s = 0.f;
      #pragma unroll
      for (int j = 0; j < N_SZ; ++j) {
        const float wj = w_sm[i * 16 + j];
        s += wj * act_sm[j * 8 + a] + (1.f - wj) * pol_sm[j * 8 + a];
      }
      sumz_sm[tid] = s;
    }
    __syncthreads();

    // --- phase 3b: row tid's z-tail in registers ---
    float o8[8];
    {
      const int i = tid >> 4, k = tid & 15;
      #pragma unroll
      for (int a = 0; a < A_SZ; ++a) {
        const float zg = wv * act_sm[k * 8 + a] + (1.f - wv) * pol_sm[k * 8 + a];
        o8[a] = (sumz_sm[i * 8 + a] - zg + pol_sm[k * 8 + a]) * 0.0625f;
      }
    }

    // --- prefetch next b's inputs (latency hides under the store burst) ---
    if (it == 0) nxt = load_b(h, pol, act, obs, blockIdx.x + GRID, tid);

    // --- phase 4: pure-register store burst (all of row-range for this b) ---
    {
      float* bb = out_obs + (size_t)b * (256 * ROW_OUT);
      // z-tails first (same burst window as heads -> DRAM-row local)
      const f32x4 lo = {o8[0], o8[1], o8[2], o8[3]};
      const f32x4 hi = {o8[4], o8[5], o8[6], o8[7]};
      f32x4* tp = (f32x4*)(bb + (size_t)tid * ROW_OUT + D_OBS);
      __builtin_nontemporal_store(lo, tp);
      __builtin_nontemporal_store(hi, tp + 1);
      // obs replication: thread's two float4s to 16 rows each
      const int k0 = tid >> 5, d4 = tid & 31;
      f32x4* b4 = (f32x4*)bb;
      #pragma unroll
      for (int i = 0; i < 16; ++i) {
        __builtin_nontemporal_store(cur.o0, b4 + (size_t)(i * 16 + k0) * 34 + d4);
        __builtin_nontemporal_store(cur.o1, b4 + (size_t)(i * 16 + k0 + 8) * 34 + d4);
      }
    }

    __syncthreads();   // small LDS reused next iteration
    cur = nxt;
  }
}

// ---------------------------------------------------------------------------
extern "C" void kernel_launch(void* const* d_in, const int* in_sizes, int n_in,
                              void* d_out, int out_size, void* d_ws, size_t ws_size,
                              hipStream_t stream) {
  const float* h      = (const float*)d_in[0];
  const float* pol    = (const float*)d_in[1];
  const float* act    = (const float*)d_in[2];
  const float* obs    = (const float*)d_in[3];
  const float* W_fc   = (const float*)d_in[4];
  const float* W_attn = (const float*)d_in[5];

  float* out = (float*)d_out;
  float* out_w = out + (size_t)B_SZ * N_SZ * N_SZ * ROW_OUT;  // 142,606,336
  float* v = (float*)d_ws;  // 256 floats

  prep_v<<<1, 1024, 0, stream>>>(W_fc, W_attn, v);
  gat_fused<<<GRID, 256, 0, stream>>>(h, pol, act, obs, v, out, out_w);
}

// Round 9
// 138.453 us; speedup vs baseline: 1.8563x; 1.8563x over previous
//
#include <hip/hip_runtime.h>
#include <math.h>

// Sizes from the reference
#define B_SZ 4096
#define N_SZ 16
#define A_SZ 8
#define IN_DIM 128
#define OUT_DIM 128
#define D_OBS 128
#define ROW_OUT (D_OBS + A_SZ)   // 136 floats = 34 float4

// Native clang vector (required by __builtin_nontemporal_*)
typedef float f32x4 __attribute__((ext_vector_type(4)));

// ---------------------------------------------------------------------------
// Kernel 1: fold W_attn into W_fc.
//   v_src[i] = sum_o W_fc[o,i]*W_attn[o]; v_dst[i] = sum_o W_fc[o,i]*W_attn[128+o]
// ---------------------------------------------------------------------------
__global__ __launch_bounds__(1024) void prep_v(const float* __restrict__ W_fc,
                                               const float* __restrict__ W_attn,
                                               float* __restrict__ v) {
  __shared__ float part[8][2][128];
  const int i = threadIdx.x & 127;
  const int seg = threadIdx.x >> 7;
  float s = 0.f, d = 0.f;
  #pragma unroll
  for (int oo = 0; oo < 16; ++oo) {
    const int o = seg * 16 + oo;
    const float w = W_fc[o * IN_DIM + i];
    s += w * W_attn[o];
    d += w * W_attn[OUT_DIM + o];
  }
  part[seg][0][i] = s;
  part[seg][1][i] = d;
  __syncthreads();
  if (seg == 0) {
    float ss = 0.f, dd = 0.f;
    #pragma unroll
    for (int t = 0; t < 8; ++t) { ss += part[t][0][i]; dd += part[t][1][i]; }
    v[i] = ss;
    v[IN_DIM + i] = dd;
  }
}

// ---------------------------------------------------------------------------
// Kernel 2: one block per batch element (R3 structure). XCD-swizzled b so the
// ~256 co-resident blocks per XCD write one dense moving band; plain (cached)
// stores so each XCD's L2 aggregates full lines and evicts sequentially.
// ---------------------------------------------------------------------------
__global__ __launch_bounds__(256) void gat_main(
    const float* __restrict__ h,        // [B,16,128]
    const float* __restrict__ pol,      // [B,16,8]
    const float* __restrict__ act,      // [B,16,8]
    const float* __restrict__ obs,      // [B*16,128]
    const float* __restrict__ v,        // [256] (v_src | v_dst)
    float* __restrict__ out_obs,        // [B*16,16,136]
    float* __restrict__ out_w)          // [B*16,16,1]
{
  // XCD-bijective swizzle: XCD x (= bid%8) gets contiguous b-slab [x*512, x*512+512)
  const int b = ((blockIdx.x & 7) << 9) | (blockIdx.x >> 3);
  const int tid = threadIdx.x;

  __shared__ float a_src_sm[16];
  __shared__ float a_dst_sm[16];
  __shared__ float w_sm[256];        // [i][j]
  __shared__ float pol_sm[128];      // [j][a]
  __shared__ float act_sm[128];
  __shared__ float sumz_sm[128];     // [i][a]
  __shared__ float outz_sm[2048];    // [i][k][a]
  __shared__ float obs_sm[2048];     // [k][d]

  // --- stage obs tile (16x128 = 512 x 16B), streaming loads ---
  {
    const f32x4* op = (const f32x4*)(obs + (size_t)b * (N_SZ * D_OBS));
    f32x4* od = (f32x4*)obs_sm;
    od[tid]       = __builtin_nontemporal_load(&op[tid]);
    od[tid + 256] = __builtin_nontemporal_load(&op[tid + 256]);
  }
  // --- stage policies / actions (128 floats each) ---
  if (tid < 128) {
    pol_sm[tid] = __builtin_nontemporal_load(&pol[(size_t)b * (N_SZ * A_SZ) + tid]);
    act_sm[tid] = __builtin_nontemporal_load(&act[(size_t)b * (N_SZ * A_SZ) + tid]);
  }

  // --- phase 1: a_src/a_dst. 16 lanes per row, 8 elems per lane. ---
  {
    const int l = tid & 15;       // lane-in-row
    const f32x4* hp = (const f32x4*)(h + (size_t)b * (N_SZ * IN_DIM));
    const f32x4 h0 = __builtin_nontemporal_load(&hp[tid * 2]);
    const f32x4 h1 = __builtin_nontemporal_load(&hp[tid * 2 + 1]);
    const f32x4* vs = (const f32x4*)v;
    const f32x4* vd = (const f32x4*)(v + IN_DIM);
    const f32x4 s0 = vs[l * 2], s1 = vs[l * 2 + 1];   // v: hot, keep cached
    const f32x4 d0 = vd[l * 2], d1 = vd[l * 2 + 1];
    float s = h0.x * s0.x + h0.y * s0.y + h0.z * s0.z + h0.w * s0.w
            + h1.x * s1.x + h1.y * s1.y + h1.z * s1.z + h1.w * s1.w;
    float d = h0.x * d0.x + h0.y * d0.y + h0.z * d0.z + h0.w * d0.w
            + h1.x * d1.x + h1.y * d1.y + h1.z * d1.z + h1.w * d1.w;
    for (int m = 8; m >= 1; m >>= 1) {
      s += __shfl_xor(s, m, 16);
      d += __shfl_xor(d, m, 16);
    }
    if (l == 0) {
      a_src_sm[tid >> 4] = s;
      a_dst_sm[tid >> 4] = d;
    }
  }
  __syncthreads();

  // --- phase 2: w[i][j] = sigmoid(leaky_relu(a_src[j] + a_dst[i], 0.01)) ---
  {
    float e = a_src_sm[tid & 15] + a_dst_sm[tid >> 4];
    e = (e >= 0.f) ? e : 0.01f * e;
    const float wv = 1.f / (1.f + expf(-e));
    w_sm[tid] = wv;
    out_w[(size_t)b * 256 + tid] = wv;   // output 1, coalesced, cached store
  }
  __syncthreads();

  // --- phase 3a: sum_z[i][a] = sum_j (w[i][j]*act[j][a] + (1-w)*pol[j][a]) ---
  if (tid < 128) {
    const int i = tid >> 3, a = tid & 7;
    float s = 0.f;
    #pragma unroll
    for (int j = 0; j < N_SZ; ++j) {
      const float wv = w_sm[i * 16 + j];
      s += wv * act_sm[j * 8 + a] + (1.f - wv) * pol_sm[j * 8 + a];
    }
    sumz_sm[tid] = s;
  }
  __syncthreads();

  // --- phase 3b: out_z[i][k][a] = (sum_z[i][a] - zg[i][k][a] + pol[k][a])/16 ---
  {
    const int i = tid >> 4, k = tid & 15;
    const float wv = w_sm[tid];   // w[i][k]
    #pragma unroll
    for (int a = 0; a < A_SZ; ++a) {
      const float zg = wv * act_sm[k * 8 + a] + (1.f - wv) * pol_sm[k * 8 + a];
      outz_sm[tid * 8 + a] =
          (sumz_sm[i * 8 + a] - zg + pol_sm[k * 8 + a]) * 0.0625f;
    }
  }
  __syncthreads();

  // --- phase 4: flat sequential write, 256 rows x 34 x 16B contiguous. ---
  // Full-line coverage per wave instruction (no partial-line stores!).
  // Incremental r/d4 (div-free after the first): idx += 256 -> r += 7,
  // d4 += 18, carry if d4 >= 34.
  float* ob = out_obs + (size_t)b * (256 * ROW_OUT);
  const f32x4* obs4 = (const f32x4*)obs_sm;
  {
    int r  = tid / 34;            // one-time magic-mul div
    int d4 = tid - r * 34;
    #pragma unroll 2
    for (int idx = tid; idx < 256 * 34; idx += 256) {
      f32x4 o4;
      if (d4 < 32) {
        o4 = obs4[(r & 15) * 32 + d4];
      } else {
        o4 = *(const f32x4*)(outz_sm + r * 8 + (d4 - 32) * 4);
      }
      *(f32x4*)(ob + (size_t)idx * 4) = o4;   // plain store -> L2 aggregates
      r += 7; d4 += 18;
      if (d4 >= 34) { d4 -= 34; ++r; }
    }
  }
}

// ---------------------------------------------------------------------------
extern "C" void kernel_launch(void* const* d_in, const int* in_sizes, int n_in,
                              void* d_out, int out_size, void* d_ws, size_t ws_size,
                              hipStream_t stream) {
  const float* h      = (const float*)d_in[0];
  const float* pol    = (const float*)d_in[1];
  const float* act    = (const float*)d_in[2];
  const float* obs    = (const float*)d_in[3];
  const float* W_fc   = (const float*)d_in[4];
  const float* W_attn = (const float*)d_in[5];

  float* out = (float*)d_out;
  float* out_w = out + (size_t)B_SZ * N_SZ * N_SZ * ROW_OUT;  // 142,606,336
  float* v = (float*)d_ws;  // 256 floats

  prep_v<<<1, 1024, 0, stream>>>(W_fc, W_attn, v);
  gat_main<<<B_SZ, 256, 0, stream>>>(h, pol, act, obs, v, out, out_w);
}